// Round 8
// baseline (344.357 us; speedup 1.0000x reference)
//
#include <hip/hip_runtime.h>
#include <hip/hip_bf16.h>

// Problem dims (fixed by setup_inputs): B=4, S=2048, DIN=4096, DOUT=4096, GS=32
#define DIN   4096
#define DOUT  4096
#define MROWS 8192            // B*S
#define GSIZE 32
#define NGPR  (DIN / GSIZE)   // groups per row = 128
#define NG_ACT (MROWS * NGPR) // 1048576
#define NG_W   (DOUT * NGPR)  // 524288

typedef __bf16 bf16_t;
typedef __attribute__((ext_vector_type(8))) __bf16 bf16x8;
typedef __attribute__((ext_vector_type(4))) float f32x4;

typedef const __attribute__((address_space(1))) void* gptr_t;
typedef __attribute__((address_space(3))) void* lptr_t;

// floor(log2(max(a,1))) grid rounding to the FP4 E2M1 set {0,±0.5,1,1.5,2,3,4,6}
__device__ __forceinline__ float fp4_round(float y) {
  float a  = __builtin_fabsf(y);
  float am = fmaxf(a, 1.0f);
  int   e  = (int)((__float_as_uint(am) >> 23) & 255u) - 127;  // floor(log2(max(a,1)))
  float step = __uint_as_float((unsigned)(e - 1 + 127) << 23); // 2^(e-1): 0.5, 1, 2
  float q = rintf(a / step) * step;  // RNE, matches jnp.round
  q = fminf(q, 6.0f);
  return copysignf(q, y);
}

// ---------------- activation quant: one thread per group of 32 ----------------
__global__ __launch_bounds__(256) void act_quant(const float* __restrict__ x,
                                                 bf16_t* __restrict__ xq,
                                                 float* __restrict__ exps_out) {
  int g = blockIdx.x * 256 + threadIdx.x;
  const float4* xp = reinterpret_cast<const float4*>(x) + (size_t)g * 8;
  float v[32];
  float amax = 0.f;
#pragma unroll
  for (int i = 0; i < 8; ++i) {
    float4 t = xp[i];
    v[4*i+0] = t.x; v[4*i+1] = t.y; v[4*i+2] = t.z; v[4*i+3] = t.w;
    amax = fmaxf(amax, fmaxf(fmaxf(__builtin_fabsf(t.x), __builtin_fabsf(t.y)),
                             fmaxf(__builtin_fabsf(t.z), __builtin_fabsf(t.w))));
  }
  float exps = 0.f;
  if (amax > 0.f) {
    float am = fmaxf(amax, 1e-30f);
    exps = (float)((int)((__float_as_uint(am) >> 23) & 255u) - 129);  // floor(log2)-2
  }
  float scale = __uint_as_float((unsigned)((int)exps + 127) << 23);   // 2^exps (exact)
  float inv   = __uint_as_float((unsigned)(127 - (int)exps) << 23);   // 2^-exps (exact)
  bf16x8 hv[4];
#pragma unroll
  for (int i = 0; i < 32; ++i) {
    float q = fp4_round(v[i] * inv) * scale;  // exact: pow2 scaling both ways
    hv[i >> 3][i & 7] = (bf16_t)q;            // exact in bf16 (<=2 mantissa bits * 2^e)
  }
  bf16x8* dst = reinterpret_cast<bf16x8*>(xq + (size_t)g * 32);
#pragma unroll
  for (int i = 0; i < 4; ++i) dst[i] = hv[i];
  exps_out[g] = exps;
}

// ---------------- weight quant with (1+eps_eff) scale ----------------
__global__ __launch_bounds__(256) void w_quant(const float* __restrict__ w,
                                               const float* __restrict__ eps,
                                               const float* __restrict__ adv,
                                               bf16_t* __restrict__ wq,
                                               float* __restrict__ eps_eff_out,
                                               float* __restrict__ w_exps_out) {
  int g = blockIdx.x * 256 + threadIdx.x;
  float ee = eps[g] + adv[g];
  eps_eff_out[g] = ee;
  const float4* wp = reinterpret_cast<const float4*>(w) + (size_t)g * 8;
  float v[32];
  float amax = 0.f;
#pragma unroll
  for (int i = 0; i < 8; ++i) {
    float4 t = wp[i];
    v[4*i+0] = t.x; v[4*i+1] = t.y; v[4*i+2] = t.z; v[4*i+3] = t.w;
    amax = fmaxf(amax, fmaxf(fmaxf(__builtin_fabsf(t.x), __builtin_fabsf(t.y)),
                             fmaxf(__builtin_fabsf(t.z), __builtin_fabsf(t.w))));
  }
  float exps = 0.f;
  if (amax > 0.f) {
    float am = fmaxf(amax, 1e-30f);
    exps = (float)((int)((__float_as_uint(am) >> 23) & 255u) - 129);
  }
  w_exps_out[g] = exps;
  float p2   = __uint_as_float((unsigned)((int)exps + 127) << 23);  // 2^exps
  float scale = p2 * (1.0f + ee);                                   // matches reference order
  bf16x8 hv[4];
#pragma unroll
  for (int i = 0; i < 32; ++i) {
    float q = fp4_round(v[i] / scale) * scale;  // IEEE div, matches reference
    hv[i >> 3][i & 7] = (bf16_t)q;              // only bf16-rounding error source
  }
  bf16x8* dst = reinterpret_cast<bf16x8*>(wq + (size_t)g * 32);
#pragma unroll
  for (int i = 0; i < 4; ++i) dst[i] = hv[i];
}

// ---------------- bf16 GEMM: C[M,N] = A[M,K] * B[N,K]^T + bias ----------------
// 256x256 tile, BK=64, 8 waves (2Mx4N), 512 thr, 128 KiB LDS double-buffer.
// r8 = PHASE-LAGGED reads (the cascade): a phase's MFMA consumes operands read
// in EARLIER phases, so derived lgkm waits are near-zero and the LDS pipe
// services phase-p's reads WHILE phase-p's MFMA runs (r4-r7 all read their own
// operands per phase -> every phase stalled on its 8-12 read burst; 37% util).
//   reads:  ph1: a-lo(8)   ph2: b-all(8)   ph3: a-hi(8)   ph4: none
//   MFMA:   ph1: Q3(j-1)=ahi*bhi  ph2: Q0=alo*blo  ph3: Q1=alo*bhi  ph4: Q2=ahi*blo
//   stage:  ph1: B-h0(j+1)->p^1   ph2: B-h1(j+1)->p^1
//           ph3: A-h0(j+2)->p     ph4: A-h1(j+2)->p
//   waits:  lgkm(0) at ph3-end (so ph4's A-h1 stage can't overwrite rows with
//           a-hi reads still outstanding); vmcnt(4) at ph4-end (retires
//           A(j+1)+B(j+1), leaves A(j+2) in flight); vmcnt(0) for j>=NT-2.
// Safety audit (per region): B(p^1) rows overwritten in ph1/ph2 were last read
// iter j-1 ph2 (retired by Q0/Q1 derived waits, 2+ barriers ago). A(p) h0
// overwritten ph3 after Q0's derived wait retired a-lo (ph2) + barrier. A(p) h1
// overwritten ph4 after explicit lgkm(0)@ph3-end + barrier.
#define NT 64   // K-tiles

__global__ __launch_bounds__(512, 2) void gemm_bt(const bf16_t* __restrict__ A,
                                                  const bf16_t* __restrict__ B,
                                                  const float* __restrict__ bias,
                                                  float* __restrict__ C) {
  __shared__ bf16_t sA[2 * 16384];
  __shared__ bf16_t sB[2 * 16384];
  const int tid  = threadIdx.x;
  const int wave = tid >> 6;   // 0..7
  const int lane = tid & 63;

  // T1: bijective XCD swizzle (512 blocks, 512 % 8 == 0)
  const int swz = (blockIdx.x & 7) * 64 + (blockIdx.x >> 3);
  const int tm0 = (swz >> 4) * 256;   // 32 M-tiles
  const int tn0 = (swz & 15) * 256;   // 16 N-tiles

  const int wr = wave >> 2;   // 0..1 : M-half (128 rows)
  const int wc = wave & 3;    // 0..3 : N-quarter (64 cols)

  // ---- half-tile staging: each wave stages 16 rows of each 128-row half ----
  // (2 x global_load_lds of 8 rows each; linear LDS dest, T2 pre-swizzled src)
  const int lrow8 = lane >> 3;                    // 0..7
  const int csw   = ((lane & 7) ^ lrow8) * 8;     // swizzled global k-chunk
  const bf16_t* gA = A + (size_t)(tm0 + wave * 16 + lrow8) * DIN + csw;
  const bf16_t* gB = B + (size_t)(tn0 + wave * 16 + lrow8) * DIN + csw;
  const int stg0 = wave * 1024;  // elems: (wave*16 rows) * 64 cols

#define STGH(sM, gM, d, h, kt) do {                                          \
    const bf16_t* g_ = (gM) + (size_t)(h) * 128 * DIN + (size_t)(kt) * 64;   \
    __builtin_amdgcn_global_load_lds((gptr_t)g_,                             \
        (lptr_t)((sM) + (d) * 16384 + (h) * 8192 + stg0), 16, 0, 0);         \
    __builtin_amdgcn_global_load_lds((gptr_t)(g_ + 8 * DIN),                 \
        (lptr_t)((sM) + (d) * 16384 + (h) * 8192 + stg0 + 512), 16, 0, 0);   \
  } while (0)

  // ---- fragment read offsets (bytes): phys = row*128 + 16*((kk*4+(l>>4)) ^ (l&7))
  const int arow_b = (wr * 128 + (lane & 15)) * 128;
  const int brow_b = (wc * 64 + (lane & 15)) * 128;
  const int slot0  = (((lane >> 4) ^ (lane & 7)) << 4);   // kk=0; kk=1 -> ^0x40

  f32x4 acc[8][4] = {};
  bf16x8 aA[4][2], aB[4][2], bn[4][2];   // aA=a-lo, aB=a-hi; carried across iters

  // ---- prologue: A(0),B(0) landed; A(1) in flight (steady-state invariant) ----
  STGH(sA, gA, 0, 0, 0); STGH(sA, gA, 0, 1, 0);
  STGH(sB, gB, 0, 0, 0); STGH(sB, gB, 0, 1, 0);
  STGH(sA, gA, 1, 0, 1); STGH(sA, gA, 1, 1, 1);
  asm volatile("s_waitcnt vmcnt(4)");       // A(0),B(0) retired; A(1) in flight
  __builtin_amdgcn_s_barrier();

  for (int j = 0; j < NT; ++j) {
    const int p = j & 1;
    const char* bufA = (const char*)sA + p * 32768;
    const char* bufB = (const char*)sB + p * 32768;

    // ======== ph1: read a-lo(j); stage B-h0(j+1); MFMA Q3(j-1) ========
#pragma unroll
    for (int m = 0; m < 4; ++m)
#pragma unroll
      for (int kk = 0; kk < 2; ++kk)
        aA[m][kk] = *reinterpret_cast<const bf16x8*>(bufA + arow_b + m * 2048 + (slot0 ^ (kk << 6)));
    if (j + 1 < NT) STGH(sB, gB, p ^ 1, 0, j + 1);
    __builtin_amdgcn_s_barrier();
    if (j > 0) {
      __builtin_amdgcn_s_setprio(1);
#pragma unroll
      for (int kk = 0; kk < 2; ++kk)
#pragma unroll
        for (int t = 0; t < 2; ++t)
#pragma unroll
          for (int m = 0; m < 4; ++m)
            acc[4 + m][2 + t] = __builtin_amdgcn_mfma_f32_16x16x32_bf16(aB[m][kk], bn[2 + t][kk], acc[4 + m][2 + t], 0, 0, 0);
      __builtin_amdgcn_s_setprio(0);
    }
    __builtin_amdgcn_s_barrier();

    // ======== ph2: read b-all(j); stage B-h1(j+1); MFMA Q0 = alo x blo ========
#pragma unroll
    for (int t = 0; t < 4; ++t)
#pragma unroll
      for (int kk = 0; kk < 2; ++kk)
        bn[t][kk] = *reinterpret_cast<const bf16x8*>(bufB + brow_b + t * 2048 + (slot0 ^ (kk << 6)));
    if (j + 1 < NT) STGH(sB, gB, p ^ 1, 1, j + 1);
    __builtin_amdgcn_s_barrier();
    __builtin_amdgcn_s_setprio(1);
#pragma unroll
    for (int kk = 0; kk < 2; ++kk)
#pragma unroll
      for (int t = 0; t < 2; ++t)
#pragma unroll
        for (int m = 0; m < 4; ++m)
          acc[m][t] = __builtin_amdgcn_mfma_f32_16x16x32_bf16(aA[m][kk], bn[t][kk], acc[m][t], 0, 0, 0);
    __builtin_amdgcn_s_setprio(0);
    __builtin_amdgcn_s_barrier();

    // ======== ph3: read a-hi(j); stage A-h0(j+2); MFMA Q1 = alo x bhi ========
#pragma unroll
    for (int m = 0; m < 4; ++m)
#pragma unroll
      for (int kk = 0; kk < 2; ++kk)
        aB[m][kk] = *reinterpret_cast<const bf16x8*>(bufA + arow_b + (4 + m) * 2048 + (slot0 ^ (kk << 6)));
    if (j + 2 < NT) STGH(sA, gA, p, 0, j + 2);
    __builtin_amdgcn_s_barrier();
    __builtin_amdgcn_s_setprio(1);
#pragma unroll
    for (int kk = 0; kk < 2; ++kk)
#pragma unroll
      for (int t = 0; t < 2; ++t)
#pragma unroll
        for (int m = 0; m < 4; ++m)
          acc[m][2 + t] = __builtin_amdgcn_mfma_f32_16x16x32_bf16(aA[m][kk], bn[2 + t][kk], acc[m][2 + t], 0, 0, 0);
    __builtin_amdgcn_s_setprio(0);
    asm volatile("s_waitcnt lgkmcnt(0)");   // retire a-hi reads before ph4's A-h1 stage
    __builtin_amdgcn_s_barrier();

    // ======== ph4: stage A-h1(j+2); MFMA Q2 = ahi x blo; counted vmcnt ========
    if (j + 2 < NT) STGH(sA, gA, p, 1, j + 2);
    __builtin_amdgcn_s_barrier();
    __builtin_amdgcn_s_setprio(1);
#pragma unroll
    for (int kk = 0; kk < 2; ++kk)
#pragma unroll
      for (int t = 0; t < 2; ++t)
#pragma unroll
        for (int m = 0; m < 4; ++m)
          acc[4 + m][t] = __builtin_amdgcn_mfma_f32_16x16x32_bf16(aB[m][kk], bn[t][kk], acc[4 + m][t], 0, 0, 0);
    __builtin_amdgcn_s_setprio(0);
    if (j < NT - 2) {
      asm volatile("s_waitcnt vmcnt(4)");   // A(j+1)+B(j+1) landed; A(j+2) in flight
    } else {
      asm volatile("s_waitcnt vmcnt(0)");   // tail drain
    }
    __builtin_amdgcn_s_barrier();
  }

  // ---- tail: Q3(NT-1) (operands in regs) ----
  __builtin_amdgcn_s_setprio(1);
#pragma unroll
  for (int kk = 0; kk < 2; ++kk)
#pragma unroll
    for (int t = 0; t < 2; ++t)
#pragma unroll
      for (int m = 0; m < 4; ++m)
        acc[4 + m][2 + t] = __builtin_amdgcn_mfma_f32_16x16x32_bf16(aB[m][kk], bn[2 + t][kk], acc[4 + m][2 + t], 0, 0, 0);
  __builtin_amdgcn_s_setprio(0);

  // ---- epilogue: D row=(lane>>4)*4+reg, col=lane&15 (m89-verified) ----
  const int r0 = tm0 + wr * 128 + ((lane >> 4) << 2);
  const int c0 = tn0 + wc * 64 + (lane & 15);
#pragma unroll
  for (int n = 0; n < 4; ++n) {
    float bv = bias[c0 + n * 16];
#pragma unroll
    for (int m = 0; m < 8; ++m) {
#pragma unroll
      for (int jj = 0; jj < 4; ++jj) {
        C[(size_t)(r0 + m * 16 + jj) * DOUT + c0 + n * 16] = acc[m][n][jj] + bv;
      }
    }
  }
#undef STGH
}

extern "C" void kernel_launch(void* const* d_in, const int* in_sizes, int n_in,
                              void* d_out, int out_size, void* d_ws, size_t ws_size,
                              hipStream_t stream) {
  const float* x    = (const float*)d_in[0];  // (4,2048,4096)
  const float* adv  = (const float*)d_in[1];  // (4096,128)
  const float* wfp  = (const float*)d_in[2];  // (4096,4096)
  const float* bias = (const float*)d_in[3];  // (4096,)
  const float* eps  = (const float*)d_in[4];  // (4096,128)

  float* out      = (float*)d_out;                    // 33554432
  float* eps_eff  = out + (size_t)MROWS * DOUT;       // 524288
  float* w_exps   = eps_eff + NG_W;                   // 524288
  float* act_exps = w_exps + NG_W;                    // 1048576

  bf16_t* xq = (bf16_t*)d_ws;                          // 67.1 MB
  bf16_t* wq = (bf16_t*)d_ws + (size_t)MROWS * DIN;    // +33.6 MB

  act_quant<<<NG_ACT / 256, 256, 0, stream>>>(x, xq, act_exps);
  w_quant<<<NG_W / 256, 256, 0, stream>>>(wfp, eps, adv, wq, eps_eff, w_exps);
  gemm_bt<<<dim3((MROWS / 256) * (DOUT / 256)), 512, 0, stream>>>(xq, wq, bias, out);
}